// Round 6
// baseline (4370.939 us; speedup 1.0000x reference)
//
#include <hip/hip_runtime.h>
#include <math.h>

#define SEQ 2048
#define DIM 2048
#define NH 16
#define HD 128
#define CACHEB 408
#define RECENT 204
#define PEN 0.4f
#define QK_SCALE 0.08838834764831845f  // 1/sqrt(128)
#define BIGT 0x7fffffff

typedef unsigned short u16;
typedef unsigned long long u64;
typedef __attribute__((ext_vector_type(8))) short bh8;   // 8 bf16 (4 VGPRs)
typedef __attribute__((ext_vector_type(4))) float f32x4; // MFMA acc

__device__ __forceinline__ u16 f2bf(float x) {           // RNE f32->bf16
    unsigned u = __float_as_uint(x);
    return (u16)((u + 0x7fffu + ((u >> 16) & 1u)) >> 16);
}
__device__ __forceinline__ void splitf(float x, u16& h, u16& l) {
    h = f2bf(x);
    float hf = __uint_as_float(((unsigned)h) << 16);
    l = f2bf(x - hf);
}

// ---------------- f32 -> (hi,lo) bf16 split, 4 elems/thread ---------------
__global__ __launch_bounds__(256)
void split_kernel(const float* __restrict__ src, u16* __restrict__ dh,
                  u16* __restrict__ dl, int n4)
{
    int i = blockIdx.x * 256 + threadIdx.x;
    if (i >= n4) return;
    float4 v = ((const float4*)src)[i];
    union { u16 s[4]; unsigned long long q; } oh, ol;
    splitf(v.x, oh.s[0], ol.s[0]); splitf(v.y, oh.s[1], ol.s[1]);
    splitf(v.z, oh.s[2], ol.s[2]); splitf(v.w, oh.s[3], ol.s[3]);
    ((unsigned long long*)dh)[i] = oh.q;
    ((unsigned long long*)dl)[i] = ol.q;
}

// ---------------- split-bf16 MFMA NT GEMM (direct-from-global) ------------
// Kept for QK (K=128) and PV (TRUNCA) paths.
template<bool ASPLITF32, bool BSPLITF32, bool CAUSAL, bool TRUNCA>
__global__ __launch_bounds__(256, 2)
void mfma_nt(const void* __restrict__ Ah_, const void* __restrict__ Al_,
             const void* __restrict__ Bh_, const void* __restrict__ Bl_,
             float* __restrict__ Cp, int K, int lda, int ldb, int ldc,
             long aB, long bB, long cB, float scale)
{
    int m0 = blockIdx.y * 128, n0 = blockIdx.x * 128;
    if (CAUSAL && n0 > m0 + 127) return;

    const float* Af = (const float*)Ah_ + (size_t)blockIdx.z * aB;
    const u16*   Ah = (const u16*)Ah_   + (size_t)blockIdx.z * aB;
    const u16*   Al = (const u16*)Al_   + (size_t)blockIdx.z * aB;
    const float* Bf = (const float*)Bh_ + (size_t)blockIdx.z * bB;
    const u16*   Bh = (const u16*)Bh_   + (size_t)blockIdx.z * bB;
    const u16*   Bl = (const u16*)Bl_   + (size_t)blockIdx.z * bB;
    float* C = Cp + (size_t)blockIdx.z * cB;

    int lane = threadIdx.x & 63, wave = threadIdx.x >> 6;
    int wm = m0 + (wave >> 1) * 64, wn = n0 + (wave & 1) * 64;
    int fr = lane & 15, quad = lane >> 4;
    int kq = quad * 8;

    auto loadA = [&](int mt, int k, bh8& h, bh8& l) {
        int r = wm + mt * 16 + fr;
        if (ASPLITF32) {
            const float* p = Af + (size_t)r * lda + k + kq;
            float4 x = *(const float4*)p, y = *(const float4*)(p + 4);
            u16 hh, ll;
            splitf(x.x,hh,ll); h[0]=(short)hh; l[0]=(short)ll;
            splitf(x.y,hh,ll); h[1]=(short)hh; l[1]=(short)ll;
            splitf(x.z,hh,ll); h[2]=(short)hh; l[2]=(short)ll;
            splitf(x.w,hh,ll); h[3]=(short)hh; l[3]=(short)ll;
            splitf(y.x,hh,ll); h[4]=(short)hh; l[4]=(short)ll;
            splitf(y.y,hh,ll); h[5]=(short)hh; l[5]=(short)ll;
            splitf(y.z,hh,ll); h[6]=(short)hh; l[6]=(short)ll;
            splitf(y.w,hh,ll); h[7]=(short)hh; l[7]=(short)ll;
        } else {
            h = *(const bh8*)(Ah + (size_t)r * lda + k + kq);
            l = *(const bh8*)(Al + (size_t)r * lda + k + kq);
        }
    };
    auto loadB = [&](int nt, int k, bh8& h, bh8& l) {
        int r = wn + nt * 16 + fr;
        if (BSPLITF32) {
            const float* p = Bf + (size_t)r * ldb + k + kq;
            float4 x = *(const float4*)p, y = *(const float4*)(p + 4);
            u16 hh, ll;
            splitf(x.x,hh,ll); h[0]=(short)hh; l[0]=(short)ll;
            splitf(x.y,hh,ll); h[1]=(short)hh; l[1]=(short)ll;
            splitf(x.z,hh,ll); h[2]=(short)hh; l[2]=(short)ll;
            splitf(x.w,hh,ll); h[3]=(short)hh; l[3]=(short)ll;
            splitf(y.x,hh,ll); h[4]=(short)hh; l[4]=(short)ll;
            splitf(y.y,hh,ll); h[5]=(short)hh; l[5]=(short)ll;
            splitf(y.z,hh,ll); h[6]=(short)hh; l[6]=(short)ll;
            splitf(y.w,hh,ll); h[7]=(short)hh; l[7]=(short)ll;
        } else {
            h = *(const bh8*)(Bh + (size_t)r * ldb + k + kq);
            l = *(const bh8*)(Bl + (size_t)r * ldb + k + kq);
        }
    };

    f32x4 acc[4][4] = {};
    int Keff = TRUNCA ? min(K, m0 + 128) : K;

    for (int k0 = 0; k0 < Keff; k0 += 32) {
        bh8 ah[4], al[4], bh[4], bl[4];
        #pragma unroll
        for (int i = 0; i < 4; i++) { loadA(i, k0, ah[i], al[i]); loadB(i, k0, bh[i], bl[i]); }
        #pragma unroll
        for (int mt = 0; mt < 4; mt++)
            #pragma unroll
            for (int nt = 0; nt < 4; nt++) {
                acc[mt][nt] = __builtin_amdgcn_mfma_f32_16x16x32_bf16(ah[mt], bh[nt], acc[mt][nt], 0, 0, 0);
                acc[mt][nt] = __builtin_amdgcn_mfma_f32_16x16x32_bf16(ah[mt], bl[nt], acc[mt][nt], 0, 0, 0);
                acc[mt][nt] = __builtin_amdgcn_mfma_f32_16x16x32_bf16(al[mt], bh[nt], acc[mt][nt], 0, 0, 0);
            }
    }

    #pragma unroll
    for (int mt = 0; mt < 4; mt++)
        #pragma unroll
        for (int r = 0; r < 4; r++) {
            int row = wm + mt * 16 + quad * 4 + r;
            #pragma unroll
            for (int nt = 0; nt < 4; nt++) {
                int col = wn + nt * 16 + fr;
                C[(size_t)row * ldc + col] = acc[mt][nt][r] * scale;
            }
        }
}

// ---------------- split-bf16 MFMA NT GEMM, LDS-staged (2048^3 only) -------
__global__ __launch_bounds__(256, 2)
void gemm_nt_staged(const u16* __restrict__ Ah, const u16* __restrict__ Al,
                    const u16* __restrict__ Bh, const u16* __restrict__ Bl,
                    float* __restrict__ C, float scale)
{
    __shared__ u16 sm[2][4][128 * 32];   // [buf][Ah,Al,Bh,Bl][row*32+col], 64 KB

    int m0 = blockIdx.y * 128, n0 = blockIdx.x * 128;
    int tid = threadIdx.x;
    int lane = tid & 63, wave = tid >> 6;
    int fr = lane & 15, quad = lane >> 4;
    int wmr = (wave >> 1) * 64;
    int wnr = (wave & 1) * 64;

    auto stage = [&](int buf, int k0) {
        #pragma unroll
        for (int a = 0; a < 4; a++) {
            const u16* g = (a == 0) ? Ah : (a == 1) ? Al : (a == 2) ? Bh : Bl;
            int r0 = (a < 2) ? m0 : n0;
            #pragma unroll
            for (int hf = 0; hf < 2; hf++) {
                int c = hf * 256 + wave * 64 + lane;
                const u16* src = g + (size_t)(r0 + (c >> 2)) * DIM + k0 + (c & 3) * 8;
                u16* dst = &sm[buf][a][(hf * 256 + wave * 64) * 8];
                __builtin_amdgcn_global_load_lds(
                    (const __attribute__((address_space(1))) void*)src,
                    (__attribute__((address_space(3))) void*)dst, 16, 0, 0);
            }
        }
    };

    f32x4 acc[4][4] = {};

    auto cmpt = [&](int buf) {
        bh8 ah[4], al[4], bhf[4], blf[4];
        #pragma unroll
        for (int i = 0; i < 4; i++) {
            int ra = (wmr + i * 16 + fr) * 32 + quad * 8;
            int rb = (wnr + i * 16 + fr) * 32 + quad * 8;
            ah[i]  = *(const bh8*)&sm[buf][0][ra];
            al[i]  = *(const bh8*)&sm[buf][1][ra];
            bhf[i] = *(const bh8*)&sm[buf][2][rb];
            blf[i] = *(const bh8*)&sm[buf][3][rb];
        }
        #pragma unroll
        for (int mt = 0; mt < 4; mt++)
            #pragma unroll
            for (int nt = 0; nt < 4; nt++) {
                acc[mt][nt] = __builtin_amdgcn_mfma_f32_16x16x32_bf16(ah[mt], bhf[nt], acc[mt][nt], 0, 0, 0);
                acc[mt][nt] = __builtin_amdgcn_mfma_f32_16x16x32_bf16(ah[mt], blf[nt], acc[mt][nt], 0, 0, 0);
                acc[mt][nt] = __builtin_amdgcn_mfma_f32_16x16x32_bf16(al[mt], bhf[nt], acc[mt][nt], 0, 0, 0);
            }
    };

    stage(0, 0);
    __syncthreads();
    int cur = 0;
    for (int k0 = 0; k0 < DIM; k0 += 32) {
        if (k0 + 32 < DIM) stage(cur ^ 1, k0 + 32);
        cmpt(cur);
        __syncthreads();
        cur ^= 1;
    }

    int wm = m0 + wmr, wn = n0 + wnr;
    #pragma unroll
    for (int mt = 0; mt < 4; mt++)
        #pragma unroll
        for (int r = 0; r < 4; r++) {
            int row = wm + mt * 16 + quad * 4 + r;
            #pragma unroll
            for (int nt = 0; nt < 4; nt++) {
                int col = wn + nt * 16 + fr;
                C[(size_t)row * DIM + col] = acc[mt][nt][r] * scale;
            }
        }
}

// ---------------- RoPE in place on Q and K (f32) ---------------------------
__global__ __launch_bounds__(256)
void rope_qk(float* __restrict__ Q, float* __restrict__ K, const int* __restrict__ pos_ids)
{
    int s = blockIdx.x;
    int i = threadIdx.x & 63;
    int h = blockIdx.y * 4 + (threadIdx.x >> 6);
    double p = (double)pos_ids[s];
    double invf = exp(-((double)(2 * i) / (double)HD) * 9.210340371976184); // ln(10000)
    double ang = p * invf;
    float c = (float)cos(ang), sn = (float)sin(ang);
    size_t b = (size_t)s * DIM + (size_t)h * HD;
    float q0 = Q[b + i], q1 = Q[b + i + 64];
    Q[b + i]      = q0 * c - q1 * sn;
    Q[b + i + 64] = q1 * c + q0 * sn;
    float k0 = K[b + i], k1 = K[b + i + 64];
    K[b + i]      = k0 * c - k1 * sn;
    K[b + i + 64] = k1 * c + k0 * sn;
}

// ---------------- V(f32) -> Vt hi/lo bf16 [h][hd][s] -----------------------
__global__ __launch_bounds__(1024)
void transpose_v(const float* __restrict__ V, u16* __restrict__ Vth, u16* __restrict__ Vtl)
{
    __shared__ float tile[32][33];
    int h = blockIdx.z;
    int j0 = blockIdx.x * 32, d0 = blockIdx.y * 32;
    int tx = threadIdx.x, ty = threadIdx.y;
    tile[ty][tx] = V[(size_t)(j0 + ty) * DIM + (size_t)h * HD + d0 + tx];
    __syncthreads();
    u16 hh, ll; splitf(tile[tx][ty], hh, ll);
    size_t idx = (size_t)h * HD * SEQ + (size_t)(d0 + ty) * SEQ + j0 + tx;
    Vth[idx] = hh; Vtl[idx] = ll;
}

// ---------------- row softmax (causal) in place on Sc ---------------------
__global__ __launch_bounds__(256)
void softmax_rows(float* __restrict__ Sc)
{
    int r = blockIdx.x, h = blockIdx.y;
    float* row = Sc + ((size_t)h * SEQ + r) * SEQ;
    int n = r + 1;
    __shared__ float red[256];
    int tid = threadIdx.x;
    float mx = -INFINITY;
    for (int j = tid; j < n; j += 256) mx = fmaxf(mx, row[j]);
    red[tid] = mx; __syncthreads();
    for (int s = 128; s; s >>= 1) { if (tid < s) red[tid] = fmaxf(red[tid], red[tid + s]); __syncthreads(); }
    mx = red[0]; __syncthreads();
    float sum = 0.f;
    for (int j = tid; j < n; j += 256) { float e = expf(row[j] - mx); row[j] = e; sum += e; }
    red[tid] = sum; __syncthreads();
    for (int s = 128; s; s >>= 1) { if (tid < s) red[tid] += red[tid + s]; __syncthreads(); }
    float inv = 1.f / red[0];
    for (int j = tid; j < n; j += 256) row[j] *= inv;
    for (int j = n + tid; j < SEQ; j += 256) row[j] = 0.f;
}

// ---------------- parallel warmup: select0[h][c] = sum_t PEN^(407-t)*Sc[t][c]
__global__ __launch_bounds__(256)
void warmup_select(const float* __restrict__ Sc, float* __restrict__ sel0)
{
    int h = blockIdx.y;
    int col = blockIdx.x * 256 + threadIdx.x;
    const float* S = Sc + (size_t)h * SEQ * SEQ + col;
    float s = 0.f;
    #pragma unroll 4
    for (int t = 0; t < CACHEB; t++) s = PEN * s + S[(size_t)t * SEQ];
    sel0[h * SEQ + col] = s;
}

// ---------------- DPP cross-lane helpers ----------------------------------
#define DPP_SUMSTEP(x, ctrl) \
    x += __int_as_float(__builtin_amdgcn_update_dpp(0, __float_as_int(x), ctrl, 0xF, 0xF, true))
#define DPP_SUMBC(x, ctrl) \
    x += __int_as_float(__builtin_amdgcn_update_dpp(0, __float_as_int(x), ctrl, 0xF, 0xF, false))

__device__ __forceinline__ float wave_sum64(float x) {
    DPP_SUMSTEP(x, 0x111); DPP_SUMSTEP(x, 0x112);
    DPP_SUMSTEP(x, 0x114); DPP_SUMSTEP(x, 0x118);
    DPP_SUMBC(x, 0x142);   DPP_SUMBC(x, 0x143);
    return __int_as_float(__builtin_amdgcn_readlane(__float_as_int(x), 63));
}

// 64-bit (value,pos) key min-reduction across the wave.
#define DPP_MIN_U64(x, ctrl) do { \
    unsigned lo_ = (unsigned)(x), hi_ = (unsigned)((x) >> 32); \
    unsigned nlo_ = (unsigned)__builtin_amdgcn_update_dpp((int)lo_, (int)lo_, ctrl, 0xF, 0xF, false); \
    unsigned nhi_ = (unsigned)__builtin_amdgcn_update_dpp((int)hi_, (int)hi_, ctrl, 0xF, 0xF, false); \
    u64 o_ = ((u64)nhi_ << 32) | nlo_; \
    if (o_ < (x)) (x) = o_; \
} while (0)

__device__ __forceinline__ u64 wave_min64_u64(u64 x) {
    DPP_MIN_U64(x, 0x111); DPP_MIN_U64(x, 0x112);
    DPP_MIN_U64(x, 0x114); DPP_MIN_U64(x, 0x118);
    DPP_MIN_U64(x, 0x142); DPP_MIN_U64(x, 0x143);
    unsigned rlo = (unsigned)__builtin_amdgcn_readlane((int)(unsigned)x, 63);
    unsigned rhi = (unsigned)__builtin_amdgcn_readlane((int)(unsigned)(x >> 32), 63);
    return ((u64)rhi << 32) | rlo;
}

// sign-extend bit k of msk to all 32 bits (0 or 0xFFFFFFFF)
#define SEXT_BIT(msk, k) ((unsigned)(((int)((msk) << (31 - (k)))) >> 31))

// ---------------- H2O scan: 4-wave parallel step, bit-exact ----------------
// The only order-sensitive float op is the row sum `part`: wave 0 computes it
// with the VERBATIM scan6 code (same per-lane order, same DPP tree). All other
// float ops are per-element (gating/decay/fmaf: exact regardless of who
// computes them) and the u64-key argmin is exact integer min (associative, any
// topology). Each wave owns a 512-column slice (8 elems/lane) for the
// sel/key/argmin work -> per-step serial VALU drops ~4x. Two barriers/step
// exchange {part} and {per-wave min keys} through LDS.
__global__ __launch_bounds__(256, 1)
void h2o_scan8(const float* __restrict__ Sc, const float* __restrict__ sel0,
               int* __restrict__ evict)
{
    __shared__ int et[SEQ];               // 8 KB
    __shared__ float pshare;
    __shared__ u64 keys[4];

    int h = blockIdx.x;
    int tid = threadIdx.x;
    int w = tid >> 6, l = tid & 63;
    const float* Sh = Sc + (size_t)h * SEQ * SEQ;
    const float* gbf = Sh + (l << 2);             // wave0 full-row base
    const float* gbs = Sh + w * 512 + (l << 2);   // slice base

    #pragma unroll
    for (int s = 0; s < SEQ / 256; s++) et[s * 256 + tid] = BIGT;

    // slice state: 8 positions/lane: j=0..3 -> col w*512+l*4+(j&3), j=4..7 -> +256
    float sel[8];
    {
        const float* s0 = sel0 + h * SEQ + w * 512 + l * 4;
        float4 v0 = *(const float4*)(s0);
        float4 v1 = *(const float4*)(s0 + 256);
        sel[0]=v0.x; sel[1]=v0.y; sel[2]=v0.z; sel[3]=v0.w;
        sel[4]=v1.x; sel[5]=v1.y; sel[6]=v1.z; sel[7]=v1.w;
    }
    unsigned pos32[8];
    unsigned smask = 0xffu, scand = 0;
    #pragma unroll
    for (int j = 0; j < 8; j++) {
        int p = w * 512 + ((j >> 2) << 8) + l * 4 + (j & 3);
        pos32[j] = (unsigned)p;
        if (p <= CACHEB - RECENT) scand |= 1u << j;
    }
    unsigned fmask = 0xffffffffu;   // wave0 only: full gating mask (layout = scan6)

    float4 fA[8], fB[8], fC[8], fD[8];   // wave0 full-row buffers
    float4 sA[2], sB[2], sC[2], sD[2];   // slice buffers (waves 1-3)

    auto loadrow = [&](int r, float4 (&fb)[8], float4 (&sb)[2]) {
        if (w == 0) {
            const float* g = gbf + (size_t)r * SEQ;
            #pragma unroll
            for (int i = 0; i < 8; i++) fb[i] = *(const float4*)(g + i * 256);
        } else {
            const float* g = gbs + (size_t)r * SEQ;
            sb[0] = *(const float4*)g;
            sb[1] = *(const float4*)(g + 256);
        }
    };
    loadrow(CACHEB + 0, fA, sA);
    loadrow(CACHEB + 1, fB, sB);
    loadrow(CACHEB + 2, fC, sC);
    loadrow(CACHEB + 3, fD, sD);

    auto step = [&](int t, float4 (&fcur)[8], float4 (&scur)[2]) {
        float m8[8];
        if (w == 0) {
            // ---- verbatim scan6 gated sum (order-critical) ----
            float m[32];
            float p0 = 0.f, p1 = 0.f, p2 = 0.f, p3 = 0.f;
            #pragma unroll
            for (int i = 0; i < 8; i++) {
                float4 b = fcur[i];
                m[i*4+0] = __uint_as_float(__float_as_uint(b.x) & SEXT_BIT(fmask, i*4+0));
                m[i*4+1] = __uint_as_float(__float_as_uint(b.y) & SEXT_BIT(fmask, i*4+1));
                m[i*4+2] = __uint_as_float(__float_as_uint(b.z) & SEXT_BIT(fmask, i*4+2));
                m[i*4+3] = __uint_as_float(__float_as_uint(b.w) & SEXT_BIT(fmask, i*4+3));
                p0 += m[i*4+0]; p1 += m[i*4+1]; p2 += m[i*4+2]; p3 += m[i*4+3];
            }
            float part = wave_sum64((p0 + p1) + (p2 + p3));
            if (l == 0) pshare = part;
            // wave0's slice (cols 0..511) = full-layout m[0..7]
            #pragma unroll
            for (int j = 0; j < 8; j++) m8[j] = m[j];
        } else {
            m8[0] = __uint_as_float(__float_as_uint(scur[0].x) & SEXT_BIT(smask, 0));
            m8[1] = __uint_as_float(__float_as_uint(scur[0].y) & SEXT_BIT(smask, 1));
            m8[2] = __uint_as_float(__float_as_uint(scur[0].z) & SEXT_BIT(smask, 2));
            m8[3] = __uint_as_float(__float_as_uint(scur[0].w) & SEXT_BIT(smask, 3));
            m8[4] = __uint_as_float(__float_as_uint(scur[1].x) & SEXT_BIT(smask, 4));
            m8[5] = __uint_as_float(__float_as_uint(scur[1].y) & SEXT_BIT(smask, 5));
            m8[6] = __uint_as_float(__float_as_uint(scur[1].z) & SEXT_BIT(smask, 6));
            m8[7] = __uint_as_float(__float_as_uint(scur[1].w) & SEXT_BIT(smask, 7));
        }
        __syncthreads();                       // B1: publish part
        float inv = 1.f / pshare;              // identical instr+input on all lanes

        unsigned ncm = ~(smask & scand);
        u64 k4[4];
        #pragma unroll
        for (int j = 0; j < 4; j++) {
            float sa = fmaf(m8[j],     inv, sel[j]     * PEN); sel[j]     = sa;
            float sb = fmaf(m8[j + 4], inv, sel[j + 4] * PEN); sel[j + 4] = sb;
            unsigned ha = __float_as_uint(sa) | SEXT_BIT(ncm, j);
            unsigned hb = __float_as_uint(sb) | SEXT_BIT(ncm, j + 4);
            u64 ka = ((u64)ha << 32) | pos32[j];
            u64 kb = ((u64)hb << 32) | pos32[j + 4];
            k4[j] = ka < kb ? ka : kb;
        }
        u64 k2a = k4[0] < k4[1] ? k4[0] : k4[1];
        u64 k2b = k4[2] < k4[3] ? k4[2] : k4[3];
        u64 lmin = k2a < k2b ? k2a : k2b;
        u64 wmin = wave_min64_u64(lmin);
        if (l == 0) keys[w] = wmin;
        __syncthreads();                       // B2: publish per-wave mins

        u64 g0 = keys[0] < keys[1] ? keys[0] : keys[1];
        u64 g1 = keys[2] < keys[3] ? keys[2] : keys[3];
        u64 g = g0 < g1 ? g0 : g1;
        unsigned bpos = (unsigned)g & 0x7ffu;

        if (w == 0) {                          // full-mask update (scan6 mapping)
            int ke = (((int)(bpos >> 8)) << 2) | (int)(bpos & 3);
            if ((((int)bpos >> 2) & 63) == l) fmask &= ~(1u << ke);
        }
        if ((int)(bpos >> 9) == w && (((int)bpos >> 2) & 63) == l) {
            int j = (int)(((bpos >> 8) & 1) << 2) | (int)(bpos & 3);
            smask &= ~(1u << j);
        }
        if (tid == 0) et[bpos] = t;

        int newc = t + 1 - RECENT;
        if ((newc >> 9) == w && ((newc >> 2) & 63) == l) {
            int j = (((newc >> 8) & 1) << 2) | (newc & 3);
            scand |= 1u << j;
        }
    };

    int t = CACHEB;
    for (; t + 7 <= SEQ - 1; t += 4) {
        step(t + 0, fA, sA); loadrow(t + 4, fA, sA);
        step(t + 1, fB, sB); loadrow(t + 5, fB, sB);
        step(t + 2, fC, sC); loadrow(t + 6, fC, sC);
        step(t + 3, fD, sD); loadrow(t + 7, fD, sD);
    }
    if (t <= SEQ - 2) { step(t, fA, sA); t++; }
    if (t <= SEQ - 2) { step(t, fB, sB); t++; }
    if (t <= SEQ - 2) { step(t, fC, sC); t++; }

    __syncthreads();
    #pragma unroll
    for (int s = 0; s < SEQ / 256; s++)
        evict[h * SEQ + s * 256 + tid] = et[s * 256 + tid];
}

// ---------------- apply mask + renormalize rows >= CACHEB in place --------
__global__ __launch_bounds__(256)
void mask_renorm(float* __restrict__ Sc, const int* __restrict__ evict)
{
    int r = CACHEB + blockIdx.x;
    int h = blockIdx.y;
    float* row = Sc + ((size_t)h * SEQ + r) * SEQ;
    const int* et = evict + h * SEQ;
    int tid = threadIdx.x;
    __shared__ float red[256];
    float v[8]; float sum = 0.f;
    #pragma unroll
    for (int s = 0; s < 8; s++) {
        int c = s * 256 + tid;
        float x = row[c];
        v[s] = (et[c] >= r) ? x : 0.f;
        sum += v[s];
    }
    red[tid] = sum; __syncthreads();
    for (int s = 128; s; s >>= 1) { if (tid < s) red[tid] += red[tid + s]; __syncthreads(); }
    float inv = 1.f / red[0];
    #pragma unroll
    for (int s = 0; s < 8; s++) row[s * 256 + tid] = v[s] * inv;
}

extern "C" void kernel_launch(void* const* d_in, const int* in_sizes, int n_in,
                              void* d_out, int out_size, void* d_ws, size_t ws_size,
                              hipStream_t stream)
{
    const float* hidden = (const float*)d_in[0];
    const int*   pos    = (const int*)d_in[2];
    const float* wq     = (const float*)d_in[3];
    const float* wk     = (const float*)d_in[4];
    const float* wv     = (const float*)d_in[5];
    const float* wo     = (const float*)d_in[6];
    float* out = (float*)d_out;

    float* ws = (float*)d_ws;
    const size_t SD = (size_t)SEQ * DIM;           // 4M elems
    float* Q    = ws;                              // f32, 16 MB
    float* K    = ws + SD;                         // f32, 16 MB
    float* V    = ws + 2 * SD;                     // f32; becomes O after transpose
    float* O    = V;
    u16*   Vth  = (u16*)(ws + 3 * SD);             // bf16-hi Vt (8 MB)
    u16*   Vtl  = Vth + SD;                        // bf16-lo Vt (8 MB)
    float* sel0 = ws + 4 * SD;                     // NH*SEQ floats
    int*   evct = (int*)(ws + 4 * SD + (size_t)NH * SEQ);
    float* Sc   = ws + 4 * SD + 2 * (size_t)NH * SEQ;   // g * SEQ*SEQ floats

    // staging (hi/lo splits) in the not-yet-used Sc region: 4 arrays x SD u16
    u16* hh = (u16*)Sc;        // hidden hi (later: O hi)
    u16* hl = hh + SD;         // hidden lo (later: O lo)
    u16* wh = hl + SD;         // current weight hi (reused per weight)
    u16* wl = wh + SD;         // current weight lo

    const size_t fixedB   = (4 * SD + 2 * (size_t)NH * SEQ) * sizeof(float);
    const size_t perHeadB = (size_t)SEQ * SEQ * sizeof(float);
    int g = NH;
    while (g > 1 && fixedB + (size_t)g * perHeadB > ws_size) g >>= 1;

    const int N4 = (int)(SD / 4);
    const int CB = (N4 + 255) / 256;

    // 0-1. split + projections (weights staged sequentially), LDS-staged GEMM
    split_kernel<<<CB, 256, 0, stream>>>(hidden, hh, hl, N4);
    split_kernel<<<CB, 256, 0, stream>>>(wq, wh, wl, N4);
    gemm_nt_staged<<<dim3(16,16), 256, 0, stream>>>(hh, hl, wh, wl, Q, 1.f);
    split_kernel<<<CB, 256, 0, stream>>>(wk, wh, wl, N4);
    gemm_nt_staged<<<dim3(16,16), 256, 0, stream>>>(hh, hl, wh, wl, K, 1.f);
    split_kernel<<<CB, 256, 0, stream>>>(wv, wh, wl, N4);
    gemm_nt_staged<<<dim3(16,16), 256, 0, stream>>>(hh, hl, wh, wl, V, 1.f);

    // 2. RoPE on Q, K (f32, in place)
    rope_qk<<<dim3(SEQ, NH / 4), 256, 0, stream>>>(Q, K, pos);

    // 3. V -> Vt hi/lo (V storage then becomes O)
    transpose_v<<<dim3(SEQ / 32, HD / 32, NH), dim3(32, 32), 0, stream>>>(V, Vth, Vtl);

    // 4-8 per head-group
    for (int h0 = 0; h0 < NH; h0 += g) {
        int gc = min(g, NH - h0);
        // QK logits: f32 Q,K split in-register, causal tiles, f32 out
        mfma_nt<true,true,true,false><<<dim3(16,16,gc), 256, 0, stream>>>(
            Q + (size_t)h0 * HD, nullptr, K + (size_t)h0 * HD, nullptr, Sc, HD,
            DIM, DIM, SEQ, HD, HD, (long)SEQ * SEQ, QK_SCALE);
        softmax_rows<<<dim3(SEQ, gc), 256, 0, stream>>>(Sc);
        warmup_select<<<dim3(SEQ / 256, gc), 256, 0, stream>>>(Sc, sel0);
        h2o_scan8<<<dim3(gc), 256, 0, stream>>>(Sc, sel0, evct);
        mask_renorm<<<dim3(SEQ - CACHEB, gc), 256, 0, stream>>>(Sc, evct);
        // PV: probs f32 split in-register (K-truncated), Vt pre-split, f32 out
        mfma_nt<true,false,false,true><<<dim3(1,16,gc), 256, 0, stream>>>(
            Sc, nullptr, Vth + (size_t)h0 * HD * SEQ, Vtl + (size_t)h0 * HD * SEQ,
            O + (size_t)h0 * HD, SEQ, SEQ, SEQ, DIM,
            (long)SEQ * SEQ, (long)HD * SEQ, HD, 1.f);
    }

    // 9. final projection via staged path: pre-split O, then out = O @ wo^T.
    split_kernel<<<CB, 256, 0, stream>>>(O, hh, hl, N4);
    split_kernel<<<CB, 256, 0, stream>>>(wo, wh, wl, N4);
    gemm_nt_staged<<<dim3(16,16), 256, 0, stream>>>(hh, hl, wh, wl, out, 1.f);
}